// Round 5
// baseline (409.940 us; speedup 1.0000x reference)
//
#include <hip/hip_runtime.h>

// SDPAttention (bug-faithful: output = masked_scores @ v, NOT softmax @ v)
// B=4 H=16 S=1024 DK=64, fp32 in/out.
// R5-R8 post-mortem: attn_main (~165us) is INVARIANT to occupancy (16->32
// waves/CU), issued K/V traffic (768->256MB), blocks/CU (1->4), swizzle,
// nt-stores -- all neutral within +-6us noise; only parallelism loss (R7)
// regressed. So R9 stops speculating on the invariant and removes PROVABLE
// serial work instead:
//   - KbT eliminated: phase 1 builds K fragments straight from fp32 k
//     (same rounding math as pack_kv -> bit-identical scores). Per-wave
//     loads union to fully-contiguous 16KB per kt-iter; with rg-merge
//     (each wave owns a kt slice, computes both 16-row groups per K load)
//     issued K bytes stay 256 KB/block, same as R5's packed-bf16 path.
//   - pack kernel now packs V only: 2048 -> 1024 blocks (~halved), and
//     32 MB of KbT HBM round-trip disappears.
//   - Phase 2/3 byte-for-byte R5 (best measured); unroll 4 keeps phase-1
//     prefetch depth (R7 lesson: chain-depth collapse is the real hazard).
//   - XCD-bijective swizzle kept (K fp32 re-reads now 2x bytes; keep the
//     8-bh/XCD working set ~5MB near L2).
// d_ws: [0,8MB) VtP[bh][dt][ks][lane][8]

typedef __attribute__((ext_vector_type(4))) float floatx4;
typedef __attribute__((ext_vector_type(8))) short shortx8;
typedef __attribute__((ext_vector_type(8))) unsigned short ushortx8;

#define S_ 1024
#define D_ 64
#define NELEM_ 4194304      // B*H*S*DK
#define ATTN_OFF 4194304    // output elements before attn_weight
#define SCN 1040            // LDS score row stride (ushorts); 2080B rows (R5 value)
#define QT 32               // q rows per block

__device__ __forceinline__ unsigned short f32_to_bf16(float f) {
    union { float f; unsigned u; } a; a.f = f;
    unsigned u = a.u;
    u += 0x7fffu + ((u >> 16) & 1u);   // round-to-nearest-even
    return (unsigned short)(u >> 16);
}

__device__ __forceinline__ float bf16_to_f32(unsigned short h) {
    union { unsigned u; float f; } a; a.u = ((unsigned)h) << 16;
    return a.f;
}

__device__ __forceinline__ ushortx8 pack8u(floatx4 a, floatx4 b) {
    ushortx8 r;
    r[0] = f32_to_bf16(a[0]); r[1] = f32_to_bf16(a[1]);
    r[2] = f32_to_bf16(a[2]); r[3] = f32_to_bf16(a[3]);
    r[4] = f32_to_bf16(b[0]); r[5] = f32_to_bf16(b[1]);
    r[6] = f32_to_bf16(b[2]); r[7] = f32_to_bf16(b[3]);
    return r;
}

// ---- pre-kernel: pack V only (K now packed in-register in attn_main) ----
__global__ __launch_bounds__(256) void pack_v(const float* __restrict__ v,
                                              unsigned short* __restrict__ vtp) {
    __shared__ float tile[64][65];
    // V fp32 [bh][s][d] -> VtP fragment-major bf16 via LDS transpose
    int blk = blockIdx.x;             // 1024
    int bh = blk >> 4;
    int s0 = (blk & 15) << 6;
    int tid = threadIdx.x;
    int r  = tid >> 2;
    int c0 = (tid & 3) << 4;
    const float* src = v + ((size_t)(bh * S_ + s0 + r)) * D_ + c0;
    #pragma unroll
    for (int j = 0; j < 4; ++j) {
        floatx4 f = *(const floatx4*)(src + j * 4);
        tile[r][c0 + j*4 + 0] = f[0];
        tile[r][c0 + j*4 + 1] = f[1];
        tile[r][c0 + j*4 + 2] = f[2];
        tile[r][c0 + j*4 + 3] = f[3];
    }
    __syncthreads();
    int d  = tid >> 2;          // 0..63
    int so = (tid & 3) << 4;    // 0,16,32,48
    int dt  = d >> 4;
    int l15 = d & 15;
    ushortx8 h0, h1;
    #pragma unroll
    for (int j = 0; j < 8; ++j) h0[j] = f32_to_bf16(tile[so + j][d]);
    #pragma unroll
    for (int j = 0; j < 8; ++j) h1[j] = f32_to_bf16(tile[so + 8 + j][d]);
    int sA = s0 + so;
    int ksA = sA >> 5, qA = (sA & 31) >> 3;
    int sB = sA + 8;
    int ksB = sB >> 5, qB = (sB & 31) >> 3;
    size_t baseA = ((((size_t)bh * 4 + dt) * 32 + ksA) * 64 + qA * 16 + l15) * 8;
    size_t baseB = ((((size_t)bh * 4 + dt) * 32 + ksB) * 64 + qB * 16 + l15) * 8;
    *(ushortx8*)(vtp + baseA) = h0;
    *(ushortx8*)(vtp + baseB) = h1;
}

// ---- main: per-block = (bh, 32-row q tile); 8 waves; 2 blocks/CU ----
// Phase 1: wave w owns kt-slice [w*8, w*8+8), packs K fp32->bf16 in-reg,
//          computes BOTH 16-row groups per K load (4 MFMAs/load).
// Phase 2/3: exact R5 (rg = w&1, cg = w>>1, parity-staggered).
__global__ __launch_bounds__(512, 4) void attn_main(
    const float* __restrict__ q,
    const float* __restrict__ k,
    const int* __restrict__ mask,
    const unsigned short* __restrict__ VtP,
    float* __restrict__ out)
{
    __shared__ unsigned short sc[QT * SCN];   // 66,560 B masked scaled scores (bf16)
    __shared__ int msk[1024];

    // XCD-bijective swizzle: 2048 blocks; 256 consecutive logical blocks
    // per XCD -> 8 bh per XCD -> K fp32 + V bf16 + Q slice ~5 MB.
    int blk = ((blockIdx.x & 7) << 8) | (blockIdx.x >> 3);
    int bh  = blk >> 5;
    int q0  = (blk & 31) << 5;
    int b   = bh >> 4;
    int tid = threadIdx.x;

    msk[tid]       = mask[(b << 10) + tid];
    msk[tid + 512] = mask[(b << 10) + tid + 512];

    int w    = tid >> 6;              // 0..7
    int lane = tid & 63;
    int l15  = lane & 15;
    int quad = lane >> 4;
    int rg   = w & 1;                 // phase2/3 row-group
    int cg   = w >> 1;                // phase2/3 col-group / d-tile

    // Q fragments for BOTH row-groups (A: m=lane&15, k=quad*8+j)
    shortx8 qf0a, qf1a, qf0b, qf1b;
    {
        const float* qb0 = q + ((size_t)(bh * S_ + q0 + l15)) * D_ + quad * 8;
        const float* qb1 = qb0 + (size_t)16 * D_;
        floatx4 a0 = *(const floatx4*)(qb0);
        floatx4 a1 = *(const floatx4*)(qb0 + 4);
        floatx4 a2 = *(const floatx4*)(qb0 + 32);
        floatx4 a3 = *(const floatx4*)(qb0 + 36);
        qf0a = (shortx8)pack8u(a0, a1);
        qf1a = (shortx8)pack8u(a2, a3);
        floatx4 b0 = *(const floatx4*)(qb1);
        floatx4 b1 = *(const floatx4*)(qb1 + 4);
        floatx4 b2 = *(const floatx4*)(qb1 + 32);
        floatx4 b3 = *(const floatx4*)(qb1 + 36);
        qf0b = (shortx8)pack8u(b0, b1);
        qf1b = (shortx8)pack8u(b2, b3);
    }

    __syncthreads();

    // ---- Phase 1: Sc = scale*QK^T, masked, -> LDS bf16 ----
    // K packed in-register from fp32 (same math pack_kv used -> identical
    // scores). Each K fragment loaded once per block, feeds 4 MFMAs.
    {
        const float* kbase = k + (size_t)bh * S_ * D_;
        #pragma unroll 4
        for (int t = 0; t < 8; ++t) {
            int kt = (w << 3) + t;
            const float* p = kbase + (size_t)(kt * 16 + l15) * D_ + quad * 8;
            floatx4 f0 = *(const floatx4*)(p);
            floatx4 f1 = *(const floatx4*)(p + 4);
            floatx4 f2 = *(const floatx4*)(p + 32);
            floatx4 f3 = *(const floatx4*)(p + 36);
            shortx8 kf0 = (shortx8)pack8u(f0, f1);
            shortx8 kf1 = (shortx8)pack8u(f2, f3);
            floatx4 acc0 = {0.f, 0.f, 0.f, 0.f};
            floatx4 acc1 = {0.f, 0.f, 0.f, 0.f};
            acc0 = __builtin_amdgcn_mfma_f32_16x16x32_bf16(qf0a, kf0, acc0, 0, 0, 0);
            acc0 = __builtin_amdgcn_mfma_f32_16x16x32_bf16(qf1a, kf1, acc0, 0, 0, 0);
            acc1 = __builtin_amdgcn_mfma_f32_16x16x32_bf16(qf0b, kf0, acc1, 0, 0, 0);
            acc1 = __builtin_amdgcn_mfma_f32_16x16x32_bf16(qf1b, kf1, acc1, 0, 0, 0);
            int n0 = kt << 4;
            int mv = msk[n0 + l15];
            int col = n0 + l15;
            #pragma unroll
            for (int r = 0; r < 4; ++r) {
                // C/D: row(q within 16-tile) = quad*4+r, col(key) = lane&15
                unsigned short h0 = mv ? f32_to_bf16(acc0[r] * 0.125f)
                                       : (unsigned short)0xC61C;  // bf16(-10000)
                unsigned short h1 = mv ? f32_to_bf16(acc1[r] * 0.125f)
                                       : (unsigned short)0xC61C;
                sc[(quad * 4 + r) * SCN + col]      = h0;
                sc[(16 + quad * 4 + r) * SCN + col] = h1;
            }
        }
    }
    __syncthreads();

    // ---- Phase 2: row softmax -> attn_weight; Phase 3: O = Sc @ V ----
    // Independent (reference bug: O uses raw masked scores). Stagger by wave
    // parity so HBM-write burst (P2) overlaps MFMA/read burst (P3).
    auto phase2 = [&]() {
        float* attnb = out + ATTN_OFF + ((size_t)(bh * S_ + q0)) * S_;
        for (int rr = 0; rr < 4; ++rr) {
            int row = (w << 2) + rr;                 // w=0..7 -> rows 0..31
            const unsigned short* srow = sc + row * SCN;
            float vv[16];
            #pragma unroll
            for (int c = 0; c < 2; ++c) {
                ushortx8 h = *(const ushortx8*)(srow + (c << 9) + lane * 8);
                #pragma unroll
                for (int j = 0; j < 8; ++j) vv[c * 8 + j] = bf16_to_f32(h[j]);
            }
            float m = vv[0];
            #pragma unroll
            for (int j = 1; j < 16; ++j) m = fmaxf(m, vv[j]);
            #pragma unroll
            for (int off = 32; off; off >>= 1) m = fmaxf(m, __shfl_xor(m, off));
            float s = 0.f;
            #pragma unroll
            for (int j = 0; j < 16; ++j) { vv[j] = __expf(vv[j] - m); s += vv[j]; }
            #pragma unroll
            for (int off = 32; off; off >>= 1) s += __shfl_xor(s, off);
            float inv = 1.0f / s;
            float* arow = attnb + (size_t)row * S_ + lane * 8;
            #pragma unroll
            for (int c = 0; c < 2; ++c) {
                floatx4 o0 = { vv[c*8+0]*inv, vv[c*8+1]*inv, vv[c*8+2]*inv, vv[c*8+3]*inv };
                floatx4 o1 = { vv[c*8+4]*inv, vv[c*8+5]*inv, vv[c*8+6]*inv, vv[c*8+7]*inv };
                *(floatx4*)(arow + (c << 9))     = o0;
                *(floatx4*)(arow + (c << 9) + 4) = o1;
            }
        }
    };
    auto phase3 = [&]() {
        // wave (rg,cg): O tile rows [rg*16..), d cols [cg*16..)
        const unsigned short* vb = VtP + (((size_t)bh * 4 + cg) * 32) * (64 * 8) + lane * 8;
        const unsigned short* sr = sc + (rg * 16 + l15) * SCN + quad * 8;
        floatx4 oacc = {0.f, 0.f, 0.f, 0.f};
        #pragma unroll 4
        for (int ks = 0; ks < 32; ++ks) {
            shortx8 af = *(const shortx8*)(sr + (ks << 5));        // LDS A-frag
            shortx8 bf = *(const shortx8*)(vb + (ks << 9));        // coalesced 16B/lane
            oacc = __builtin_amdgcn_mfma_f32_16x16x32_bf16(af, bf, oacc, 0, 0, 0);
        }
        float* ob = out + ((size_t)(bh * S_ + q0 + rg * 16 + (quad << 2))) * D_
                        + (cg << 4) + l15;
        #pragma unroll
        for (int r = 0; r < 4; ++r) ob[(size_t)r * D_] = oacc[r];
    };
    if (w & 1) { phase3(); phase2(); }
    else       { phase2(); phase3(); }
}

extern "C" void kernel_launch(void* const* d_in, const int* in_sizes, int n_in,
                              void* d_out, int out_size, void* d_ws, size_t ws_size,
                              hipStream_t stream) {
    const float* q   = (const float*)d_in[0];
    const float* k   = (const float*)d_in[1];
    const float* v   = (const float*)d_in[2];
    const int* mask  = (const int*)d_in[3];
    float* out = (float*)d_out;
    unsigned short* VtP = (unsigned short*)d_ws;       // 8 MB
    pack_v<<<1024, 256, 0, stream>>>(v, VtP);
    attn_main<<<2048, 512, 0, stream>>>(q, k, mask, VtP, out);
}

// Round 6
// 366.023 us; speedup vs baseline: 1.1200x; 1.1200x over previous
//
#include <hip/hip_runtime.h>

// SDPAttention (bug-faithful: output = masked_scores @ v, NOT softmax @ v)
// B=4 H=16 S=1024 DK=64, fp32 in/out.
// R10: exact revert to R5, the best harness-verified config (366.5 us).
// Session ledger (all vs R5):
//   R6 nt-stores+swizzle+rgmerge +10.4 | R7 full dedup/1blk/CU +21.1
//   R8 32waves/CU/4blk/CU +9.8        | R9 KbT-elim (fp32 K) +43.4
// attn_main (~165us) proved INVARIANT to occupancy, issued K/V traffic,
// XCD swizzle (L3-fit => swizzle mildly negative), and store policy; the
// only effective structure is this one: Qtile 32, 512-thr blocks (8 waves
// = 2rg x 4cg), 66.5KB LDS, 2 blocks/CU, KbT/VtP bf16 pre-pack, phase2/3
// parity-staggered. KbT pre-pack is load-bearing (R9: in-loop fp32 K
// conversion costs ~45us of phase-1 critical path).
// d_ws: [0,8MB) KbT[bh][kt][lane][16]; [8MB,16MB) VtP[bh][dt][ks][lane][8]

typedef __attribute__((ext_vector_type(4))) float floatx4;
typedef __attribute__((ext_vector_type(8))) short shortx8;
typedef __attribute__((ext_vector_type(8))) unsigned short ushortx8;
typedef __attribute__((ext_vector_type(4))) int intx4;

#define S_ 1024
#define D_ 64
#define NELEM_ 4194304      // B*H*S*DK
#define ATTN_OFF 4194304    // output elements before attn_weight
#define SCN 1040            // LDS score row stride (ushorts); 2080B rows, 16B aligned
#define QT 32               // q rows per block

__device__ __forceinline__ unsigned short f32_to_bf16(float f) {
    union { float f; unsigned u; } a; a.f = f;
    unsigned u = a.u;
    u += 0x7fffu + ((u >> 16) & 1u);   // round-to-nearest-even
    return (unsigned short)(u >> 16);
}

__device__ __forceinline__ float bf16_to_f32(unsigned short h) {
    union { unsigned u; float f; } a; a.u = ((unsigned)h) << 16;
    return a.f;
}

__device__ __forceinline__ ushortx8 pack8u(floatx4 a, floatx4 b) {
    ushortx8 r;
    r[0] = f32_to_bf16(a[0]); r[1] = f32_to_bf16(a[1]);
    r[2] = f32_to_bf16(a[2]); r[3] = f32_to_bf16(a[3]);
    r[4] = f32_to_bf16(b[0]); r[5] = f32_to_bf16(b[1]);
    r[6] = f32_to_bf16(b[2]); r[7] = f32_to_bf16(b[3]);
    return r;
}

// ---- merged pre-kernel: blocks [0,1024) pack K, [1024,2048) pack V ----
__global__ __launch_bounds__(256) void pack_kv(const float* __restrict__ k,
                                               const float* __restrict__ v,
                                               unsigned short* __restrict__ kbt,
                                               unsigned short* __restrict__ vtp) {
    __shared__ float tile[64][65];
    if (blockIdx.x < 1024) {
        // K fp32 [bh][s][d] -> KbT fragment-major bf16
        int g = blockIdx.x * 256 + threadIdx.x;   // 262144 total
        int lane = g & 63;
        int kt   = (g >> 6) & 63;
        int bh   = g >> 12;
        int quad = lane >> 4;
        int l15  = lane & 15;
        const float* src = k + ((size_t)(bh * S_ + kt * 16 + l15)) * D_ + quad * 8;
        floatx4 f0 = *(const floatx4*)(src);
        floatx4 f1 = *(const floatx4*)(src + 4);
        floatx4 f2 = *(const floatx4*)(src + 32);
        floatx4 f3 = *(const floatx4*)(src + 36);
        unsigned short* dst = kbt + (size_t)g * 16;
        *(ushortx8*)(dst)     = pack8u(f0, f1);
        *(ushortx8*)(dst + 8) = pack8u(f2, f3);
    } else {
        // V fp32 [bh][s][d] -> VtP fragment-major bf16 via LDS transpose
        int blk = blockIdx.x - 1024;
        int bh = blk >> 4;
        int s0 = (blk & 15) << 6;
        int tid = threadIdx.x;
        int r  = tid >> 2;
        int c0 = (tid & 3) << 4;
        const float* src = v + ((size_t)(bh * S_ + s0 + r)) * D_ + c0;
        #pragma unroll
        for (int j = 0; j < 4; ++j) {
            floatx4 f = *(const floatx4*)(src + j * 4);
            tile[r][c0 + j*4 + 0] = f[0];
            tile[r][c0 + j*4 + 1] = f[1];
            tile[r][c0 + j*4 + 2] = f[2];
            tile[r][c0 + j*4 + 3] = f[3];
        }
        __syncthreads();
        int d  = tid >> 2;          // 0..63
        int so = (tid & 3) << 4;    // 0,16,32,48
        int dt  = d >> 4;
        int l15 = d & 15;
        ushortx8 h0, h1;
        #pragma unroll
        for (int j = 0; j < 8; ++j) h0[j] = f32_to_bf16(tile[so + j][d]);
        #pragma unroll
        for (int j = 0; j < 8; ++j) h1[j] = f32_to_bf16(tile[so + 8 + j][d]);
        int sA = s0 + so;
        int ksA = sA >> 5, qA = (sA & 31) >> 3;
        int sB = sA + 8;
        int ksB = sB >> 5, qB = (sB & 31) >> 3;
        size_t baseA = ((((size_t)bh * 4 + dt) * 32 + ksA) * 64 + qA * 16 + l15) * 8;
        size_t baseB = ((((size_t)bh * 4 + dt) * 32 + ksB) * 64 + qB * 16 + l15) * 8;
        *(ushortx8*)(vtp + baseA) = h0;
        *(ushortx8*)(vtp + baseB) = h1;
    }
}

// ---- main: per-block = (bh, 32-row q tile); 8 waves = 2 rg x 4 cg ----
__global__ __launch_bounds__(512, 4) void attn_main(
    const float* __restrict__ q,
    const int* __restrict__ mask,
    const unsigned short* __restrict__ KbT,
    const unsigned short* __restrict__ VtP,
    float* __restrict__ out)
{
    __shared__ unsigned short sc[QT * SCN];   // 66,560 B masked scaled scores (bf16)
    __shared__ int msk[1024];

    int blk = blockIdx.x;             // 2048 blocks
    int bh  = blk >> 5;
    int q0  = (blk & 31) << 5;
    int b   = bh >> 4;
    int tid = threadIdx.x;

    msk[tid]       = mask[(b << 10) + tid];
    msk[tid + 512] = mask[(b << 10) + tid + 512];

    int w    = tid >> 6;              // 0..7
    int lane = tid & 63;
    int l15  = lane & 15;
    int quad = lane >> 4;
    int rg   = w & 1;                 // row-group: q rows [rg*16, rg*16+16)
    int cg   = w >> 1;                // col-group: kt in [cg*16, cg*16+16) / d-tile cg

    // Q fragments (A: m=lane&15 (q row within tile), k=quad*8+j (d))
    shortx8 qf0, qf1;
    {
        const float* qb = q + ((size_t)(bh * S_ + q0 + rg * 16 + l15)) * D_ + quad * 8;
        floatx4 a0 = *(const floatx4*)(qb);
        floatx4 a1 = *(const floatx4*)(qb + 4);
        floatx4 b0 = *(const floatx4*)(qb + 32);
        floatx4 b1 = *(const floatx4*)(qb + 36);
        ushortx8 u0 = pack8u(a0, a1);
        ushortx8 u1 = pack8u(b0, b1);
        qf0 = (shortx8)u0;
        qf1 = (shortx8)u1;
    }

    __syncthreads();

    // ---- Phase 1: Sc = scale*QK^T, masked, -> LDS bf16 ----
    {
        const unsigned short* kb = KbT + ((size_t)bh * 64 * 64 + lane) * 16;
        #pragma unroll 4
        for (int t = 0; t < 16; ++t) {
            int kt = (cg << 4) + t;
            const unsigned short* p = kb + (size_t)kt * (64 * 16);
            shortx8 kf0 = *(const shortx8*)(p);       // coalesced: lane*32B
            shortx8 kf1 = *(const shortx8*)(p + 8);
            floatx4 acc = {0.f, 0.f, 0.f, 0.f};
            acc = __builtin_amdgcn_mfma_f32_16x16x32_bf16(qf0, kf0, acc, 0, 0, 0);
            acc = __builtin_amdgcn_mfma_f32_16x16x32_bf16(qf1, kf1, acc, 0, 0, 0);
            int n0 = kt << 4;
            int mv = msk[n0 + l15];
            int col = n0 + l15;
            #pragma unroll
            for (int r = 0; r < 4; ++r) {
                // C/D: row(q within 16-tile) = quad*4+r, col(key) = lane&15
                unsigned short h = mv ? f32_to_bf16(acc[r] * 0.125f)
                                      : (unsigned short)0xC61C;  // bf16(-10000) = -9984
                sc[(rg * 16 + quad * 4 + r) * SCN + col] = h;
            }
        }
    }
    __syncthreads();

    // ---- Phase 2: row softmax -> attn_weight; Phase 3: O = Sc @ V ----
    // Independent (reference bug: O uses raw masked scores). Stagger by wave
    // parity so HBM-write burst (P2) overlaps MFMA/read burst (P3).
    auto phase2 = [&]() {
        float* attnb = out + ATTN_OFF + ((size_t)(bh * S_ + q0)) * S_;
        for (int rr = 0; rr < 4; ++rr) {
            int row = (w << 2) + rr;                 // w=0..7 -> rows 0..31
            const unsigned short* srow = sc + row * SCN;
            float vv[16];
            #pragma unroll
            for (int c = 0; c < 2; ++c) {
                ushortx8 h = *(const ushortx8*)(srow + (c << 9) + lane * 8);
                #pragma unroll
                for (int j = 0; j < 8; ++j) vv[c * 8 + j] = bf16_to_f32(h[j]);
            }
            float m = vv[0];
            #pragma unroll
            for (int j = 1; j < 16; ++j) m = fmaxf(m, vv[j]);
            #pragma unroll
            for (int off = 32; off; off >>= 1) m = fmaxf(m, __shfl_xor(m, off));
            float s = 0.f;
            #pragma unroll
            for (int j = 0; j < 16; ++j) { vv[j] = __expf(vv[j] - m); s += vv[j]; }
            #pragma unroll
            for (int off = 32; off; off >>= 1) s += __shfl_xor(s, off);
            float inv = 1.0f / s;
            float* arow = attnb + (size_t)row * S_ + lane * 8;
            #pragma unroll
            for (int c = 0; c < 2; ++c) {
                floatx4 o0 = { vv[c*8+0]*inv, vv[c*8+1]*inv, vv[c*8+2]*inv, vv[c*8+3]*inv };
                floatx4 o1 = { vv[c*8+4]*inv, vv[c*8+5]*inv, vv[c*8+6]*inv, vv[c*8+7]*inv };
                *(floatx4*)(arow + (c << 9))     = o0;
                *(floatx4*)(arow + (c << 9) + 4) = o1;
            }
        }
    };
    auto phase3 = [&]() {
        // wave (rg,cg): O tile rows [rg*16..), d cols [cg*16..)
        const unsigned short* vb = VtP + (((size_t)bh * 4 + cg) * 32) * (64 * 8) + lane * 8;
        const unsigned short* sr = sc + (rg * 16 + l15) * SCN + quad * 8;
        floatx4 oacc = {0.f, 0.f, 0.f, 0.f};
        #pragma unroll 4
        for (int ks = 0; ks < 32; ++ks) {
            shortx8 af = *(const shortx8*)(sr + (ks << 5));        // LDS A-frag
            shortx8 bf = *(const shortx8*)(vb + (ks << 9));        // coalesced 16B/lane
            oacc = __builtin_amdgcn_mfma_f32_16x16x32_bf16(af, bf, oacc, 0, 0, 0);
        }
        float* ob = out + ((size_t)(bh * S_ + q0 + rg * 16 + (quad << 2))) * D_
                        + (cg << 4) + l15;
        #pragma unroll
        for (int r = 0; r < 4; ++r) ob[(size_t)r * D_] = oacc[r];
    };
    if (w & 1) { phase3(); phase2(); }
    else       { phase2(); phase3(); }
}

extern "C" void kernel_launch(void* const* d_in, const int* in_sizes, int n_in,
                              void* d_out, int out_size, void* d_ws, size_t ws_size,
                              hipStream_t stream) {
    const float* q   = (const float*)d_in[0];
    const float* k   = (const float*)d_in[1];
    const float* v   = (const float*)d_in[2];
    const int* mask  = (const int*)d_in[3];
    float* out = (float*)d_out;
    unsigned short* KbT = (unsigned short*)d_ws;       // 8 MB
    unsigned short* VtP = KbT + NELEM_;                // 8 MB
    pack_kv<<<2048, 256, 0, stream>>>(k, v, KbT, VtP);
    attn_main<<<2048, 512, 0, stream>>>(q, mask, KbT, VtP, out);
}